// Round 5
// baseline (750.171 us; speedup 1.0000x reference)
//
#include <hip/hip_runtime.h>
#include <math.h>

#define BB 16
#define NN 512
#define HID 32
#define KCYC 3   // (201-1)/100 + 1

#define HALO 16
#define TW 96        // logical tile width (64 + 2*HALO)
#define TWP 97       // LDS pitch: 97 % 32 == 1 -> bank-conflict-free
#define OT 64

// fast tanh-approx GELU: gelu(v) = v / (1 + exp2(K1*v + K2*v^3))
#define GELU_K1 (-2.302208201f)
#define GELU_K2 (-0.102944244f)

typedef float v2f __attribute__((ext_vector_type(2)));

// ---------------------------------------------------------------------------
// LFA map: lfa[b,i,j] = |1 - tau * S(theta1, theta2)|^5
// ---------------------------------------------------------------------------
__global__ __launch_bounds__(256) void lfa_kernel(const float* __restrict__ kernelA,
                                                  float* __restrict__ lfa) {
    int j = blockIdx.x * 256 + threadIdx.x;   // col
    int i = blockIdx.y;                       // row
    int b = blockIdx.z;
    const float* a = kernelA + b * 9;
    float a0 = a[0], a1 = a[1], a2 = a[2], a3 = a[3], a4 = a[4];
    float a5 = a[5], a6 = a[6], a7 = a[7], a8 = a[8];

    const float h = 1.0f / (float)(NN + 1);
    const float twopi_h = 6.283185307179586f * h;
    float th1 = twopi_h * (float)(j - NN / 2);
    float th2 = twopi_h * (float)(i - NN / 2);
    float s1, c1, s2, c2;
    sincosf(th1, &s1, &c1);
    sincosf(th2, &s2, &c2);

    float cpp = c1 * c2 - s1 * s2;
    float spp = s1 * c2 + c1 * s2;
    float cpm = c1 * c2 + s1 * s2;
    float spm = s1 * c2 - c1 * s2;

    float re = a4 + (a3 + a5) * c1 + (a1 + a7) * c2
             + (a0 + a8) * cpp + (a2 + a6) * cpm;
    float im = (a5 - a3) * s1 + (a7 - a1) * s2
             + (a8 - a0) * spp + (a2 - a6) * spm;

    float tau = 0.5f / a4;
    float zre = 1.0f - tau * re;
    float zim = -tau * im;
    float m2 = zre * zre + zim * zim;
    float v = m2 * m2 * sqrtf(m2);    // |z|^5

    lfa[(size_t)b * NN * NN + (size_t)i * NN + j] = v;
}

// ---------------------------------------------------------------------------
// One full cycle: 10 Jacobi sweeps (register-resident 12x3 blocks, LDS halo
// exchange only) + fused pointwise-MLP correction (thread-remapped, 1x work)
// Tile 96x96 (pitch 97), output 64x64. After sweep s rings >= s valid;
// correction windows lie in rings >= 15, valid since 10 < 15.
// __launch_bounds__(256,4): cap VGPR at 128 so 4 waves/SIMD (round-4 lesson:
// 132 VGPR halved occupancy, 119 -> 165 us).
// ---------------------------------------------------------------------------
template <bool FIRST>
__global__ __launch_bounds__(256, 4) void fused_cycle(
        const float* __restrict__ xin, float* __restrict__ xout,
        const float* __restrict__ f, const float* __restrict__ kernelA,
        const float* __restrict__ lfa,
        const float* __restrict__ W1, const float* __restrict__ b1,
        const float* __restrict__ W2, const float* __restrict__ b2) {
    __shared__ float sx[TW * TWP];
    __shared__ float swt[132];    // W1(64) | b1(32) | W2(32) | b2(1)
    const int tx = threadIdx.x;   // 0..31
    const int ty = threadIdx.y;   // 0..7
    const int t  = ty * 32 + tx;
    const int b  = blockIdx.z;
    const int gy0 = blockIdx.y * OT;
    const int gx0 = blockIdx.x * OT;
    const int goi = gy0 - HALO;
    const int goj = gx0 - HALO;
    const float* fg = f + (size_t)b * NN * NN;
    const float* ag = kernelA + b * 9;   // uniform -> s_load
    const float ar0 = ag[0], ar1 = ag[1], ar2 = ag[2], ar3 = ag[3], ar4 = ag[4];
    const float ar5 = ag[5], ar6 = ag[6], ar7 = ag[7], ar8 = ag[8];
    const float tau = 0.5f / ar4;
    // negated tau-scaled stencil (acc starts at tau*f, accumulates downward)
    const float n0 = -tau * ar0, n1 = -tau * ar1, n2 = -tau * ar2;
    const float n3 = -tau * ar3, n4 = -tau * ar4, n5 = -tau * ar5;
    const float n6 = -tau * ar6, n7 = -tau * ar7, n8 = -tau * ar8;

    // ---- weights -> LDS broadcast array (one-time) ----
    if (t < 129) {
        float w;
        if (t < 64)       w = W1[t];
        else if (t < 96)  w = b1[t - 64];
        else if (t < 128) w = W2[t - 96];
        else              w = b2[0];
        swt[t] = w;
    }

    // ---- Phase A: tile -> LDS ----
    if (FIRST) {
#pragma unroll
        for (int k = 0; k < (TW * TW) / 256; ++k) {
            int idx = t + k * 256;
            int row = idx / TW, col = idx - row * TW;
            sx[row * TWP + col] = 0.f;
        }
    } else {
        const float* xg = xin + (size_t)b * NN * NN;
#pragma unroll
        for (int k = 0; k < (TW * TW) / 256; ++k) {
            int idx = t + k * 256;
            int row = idx / TW, col = idx - row * TW;
            int gi = goi + row, gj = goj + col;
            float v = 0.f;
            if (gi >= 0 && gi < NN && gj >= 0 && gj < NN) v = xg[gi * NN + gj];
            sx[row * TWP + col] = v;
        }
    }

    const int R0 = ty * 12, C0 = tx * 3;

    // masks: cell updates only if tile-interior AND inside global domain
    float vR[12], vC[3];
#pragma unroll
    for (int r = 0; r < 12; ++r) {
        int R = R0 + r, gi = goi + R;
        vR[r] = (R >= 1 && R < TW - 1 && gi >= 0 && gi < NN) ? 1.f : 0.f;
    }
#pragma unroll
    for (int c = 0; c < 3; ++c) {
        int C = C0 + c, gj = goj + C;
        vC[c] = (C >= 1 && C < TW - 1 && gj >= 0 && gj < NN) ? 1.f : 0.f;
    }

    // tau-scaled f for owned cells (0 outside domain)
    float frt[12][3];
#pragma unroll
    for (int r = 0; r < 12; ++r) {
        int gi = goi + R0 + r;
#pragma unroll
        for (int c = 0; c < 3; ++c) {
            int gj = goj + C0 + c;
            frt[r][c] = (gi >= 0 && gi < NN && gj >= 0 && gj < NN)
                            ? tau * fg[gi * NN + gj] : 0.f;
        }
    }

    __syncthreads();   // tile + weights visible

    // ---- Phase B: own cells -> registers ----
    float cur[12][3];
    if (FIRST) {
#pragma unroll
        for (int r = 0; r < 12; ++r) { cur[r][0] = cur[r][1] = cur[r][2] = 0.f; }
    } else {
#pragma unroll
        for (int r = 0; r < 12; ++r) {
            int base = (R0 + r) * TWP + C0;
            cur[r][0] = sx[base]; cur[r][1] = sx[base + 1]; cur[r][2] = sx[base + 2];
        }
    }

    // clamped halo indices (garbage only feeds masked / already-invalid cells)
    const int rT = (R0 == 0) ? 0 : R0 - 1;
    const int rB = (R0 + 12 > TW - 1) ? TW - 1 : R0 + 12;
    const int cL = (C0 == 0) ? 0 : C0 - 1;
    const int cR = (C0 + 3 > TW - 1) ? TW - 1 : C0 + 3;

    // ---- Phase C: 10 sweeps ----
    for (int s = 0; s < 10; ++s) {
        // halo reads (34)
        float top0 = sx[rT * TWP + cL], top1 = sx[rT * TWP + C0],
              top2 = sx[rT * TWP + C0 + 1], top3 = sx[rT * TWP + C0 + 2],
              top4 = sx[rT * TWP + cR];
        float bot0 = sx[rB * TWP + cL], bot1 = sx[rB * TWP + C0],
              bot2 = sx[rB * TWP + C0 + 1], bot3 = sx[rB * TWP + C0 + 2],
              bot4 = sx[rB * TWP + cR];
        float pm0 = top1, pm1v = top2, pm2 = top3;
        float Lm1 = top0, Rm1 = top4;
        float Lc = sx[R0 * TWP + cL], Rc = sx[R0 * TWP + cR];
#pragma unroll
        for (int r = 0; r < 12; ++r) {
            float nb0, nb1, nb2, Lp, Rp;
            if (r < 11) {
                nb0 = cur[r + 1][0]; nb1 = cur[r + 1][1]; nb2 = cur[r + 1][2];
                Lp = sx[(R0 + r + 1) * TWP + cL];
                Rp = sx[(R0 + r + 1) * TWP + cR];
            } else {
                nb0 = bot1; nb1 = bot2; nb2 = bot3; Lp = bot0; Rp = bot4;
            }
            float o0 = cur[r][0], o1 = cur[r][1], o2 = cur[r][2];
            // c = 0
            {
                float acc = frt[r][0];
                acc = fmaf(n0, Lm1, acc); acc = fmaf(n1, pm0, acc);
                acc = fmaf(n2, pm1v, acc); acc = fmaf(n3, Lc, acc);
                acc = fmaf(n4, o0, acc);  acc = fmaf(n5, o1, acc);
                acc = fmaf(n6, Lp, acc);  acc = fmaf(n7, nb0, acc);
                acc = fmaf(n8, nb1, acc);
                cur[r][0] = fmaf(vR[r] * vC[0], acc, o0);
            }
            // c = 1
            {
                float acc = frt[r][1];
                acc = fmaf(n0, pm0, acc); acc = fmaf(n1, pm1v, acc);
                acc = fmaf(n2, pm2, acc); acc = fmaf(n3, o0, acc);
                acc = fmaf(n4, o1, acc);  acc = fmaf(n5, o2, acc);
                acc = fmaf(n6, nb0, acc); acc = fmaf(n7, nb1, acc);
                acc = fmaf(n8, nb2, acc);
                cur[r][1] = fmaf(vR[r] * vC[1], acc, o1);
            }
            // c = 2
            {
                float acc = frt[r][2];
                acc = fmaf(n0, pm1v, acc); acc = fmaf(n1, pm2, acc);
                acc = fmaf(n2, Rm1, acc);  acc = fmaf(n3, o1, acc);
                acc = fmaf(n4, o2, acc);   acc = fmaf(n5, Rc, acc);
                acc = fmaf(n6, nb1, acc);  acc = fmaf(n7, nb2, acc);
                acc = fmaf(n8, Rp, acc);
                cur[r][2] = fmaf(vR[r] * vC[2], acc, o2);
            }
            pm0 = o0; pm1v = o1; pm2 = o2;
            Lm1 = Lc; Rm1 = Rc; Lc = Lp; Rc = Rp;
        }
        __syncthreads();   // all halo reads done
        if (s < 9) {
            // write border cells (26)
            int bTop = R0 * TWP + C0, bBot = (R0 + 11) * TWP + C0;
            sx[bTop] = cur[0][0]; sx[bTop + 1] = cur[0][1]; sx[bTop + 2] = cur[0][2];
            sx[bBot] = cur[11][0]; sx[bBot + 1] = cur[11][1]; sx[bBot + 2] = cur[11][2];
#pragma unroll
            for (int r = 1; r < 11; ++r) {
                int base = (R0 + r) * TWP + C0;
                sx[base] = cur[r][0]; sx[base + 2] = cur[r][2];
            }
        } else {
            // final sweep: publish ALL cells for the correction phase
#pragma unroll
            for (int r = 0; r < 12; ++r) {
                int base = (R0 + r) * TWP + C0;
                sx[base] = cur[r][0]; sx[base + 1] = cur[r][1]; sx[base + 2] = cur[r][2];
            }
        }
        __syncthreads();   // writes visible
    }

    // ---- Phase D: remapped correction, exactly 1x MLP work ----
    // thread t -> output row orow = t/4 (0..63), column segment oseg = t%4 (16 cols)
    // Quad-at-a-time + float2-packed GELU loop (v_pk_fma_f32) to keep VGPRs low.
    const int orow = t >> 2;
    const int oseg = t & 3;
    const int Rl = HALO + orow;           // 16..79
    const int Cl0 = HALO + oseg * 16;     // 16,32,48,64
    float w0[18], w1[18], w2[18];
#pragma unroll
    for (int k = 0; k < 18; ++k) {
        w0[k] = sx[(Rl - 1) * TWP + Cl0 - 1 + k];
        w1[k] = sx[Rl * TWP + Cl0 - 1 + k];
        w2[k] = sx[(Rl + 1) * TWP + Cl0 - 1 + k];
    }
    const int gi = gy0 + orow;
    const int gjb = gx0 + oseg * 16;
    const float4* f4 = (const float4*)(fg + (size_t)gi * NN + gjb);
    const float4* l4 = (const float4*)(lfa + (size_t)b * NN * NN + (size_t)gi * NN + gjb);
    float4* xo4 = (float4*)(xout + (size_t)b * NN * NN + (size_t)gi * NN + gjb);
    const float b2v = swt[128];

#pragma unroll
    for (int q = 0; q < 4; ++q) {
        float4 fq = f4[q], lq = l4[q];
        float rv[4];
#pragma unroll
        for (int k4 = 0; k4 < 4; ++k4) {
            int k = q * 4 + k4;
            float ax = ar0 * w0[k];
            ax = fmaf(ar1, w0[k + 1], ax); ax = fmaf(ar2, w0[k + 2], ax);
            ax = fmaf(ar3, w1[k], ax);     ax = fmaf(ar4, w1[k + 1], ax);
            ax = fmaf(ar5, w1[k + 2], ax); ax = fmaf(ar6, w2[k], ax);
            ax = fmaf(ar7, w2[k + 1], ax); ax = fmaf(ar8, w2[k + 2], ax);
            float fk = (k4 == 0) ? fq.x : (k4 == 1) ? fq.y : (k4 == 2) ? fq.z : fq.w;
            rv[k4] = fk - ax;
        }
        v2f lvp0 = {lq.x, lq.y}, lvp1 = {lq.z, lq.w};
        v2f rvp0 = {rv[0], rv[1]}, rvp1 = {rv[2], rv[3]};
        v2f acc0 = {0.f, 0.f}, acc1 = {0.f, 0.f};
#pragma unroll 4
        for (int hh = 0; hh < HID; ++hh) {
            float w1a = swt[2 * hh], w1b = swt[2 * hh + 1];
            float bb = swt[64 + hh], wo = swt[96 + hh];
            v2f w1a2 = {w1a, w1a}, w1b2 = {w1b, w1b}, bb2 = {bb, bb};
            v2f wo2 = {wo, wo};
            v2f v0 = w1a2 * lvp0 + w1b2 * rvp0 + bb2;
            v2f v1 = w1a2 * lvp1 + w1b2 * rvp1 + bb2;
            v2f k1v = {GELU_K1, GELU_K1}, k2v = {GELU_K2, GELU_K2};
            v2f m0 = v0 * (k2v * (v0 * v0) + k1v);
            v2f m1 = v1 * (k2v * (v1 * v1) + k1v);
            v2f e0, e1;
            e0.x = __builtin_amdgcn_exp2f(m0.x); e0.y = __builtin_amdgcn_exp2f(m0.y);
            e1.x = __builtin_amdgcn_exp2f(m1.x); e1.y = __builtin_amdgcn_exp2f(m1.y);
            v2f ones = {1.f, 1.f};
            v2f d0 = e0 + ones, d1 = e1 + ones;
            v2f rc0, rc1;
            rc0.x = __builtin_amdgcn_rcpf(d0.x); rc0.y = __builtin_amdgcn_rcpf(d0.y);
            rc1.x = __builtin_amdgcn_rcpf(d1.x); rc1.y = __builtin_amdgcn_rcpf(d1.y);
            acc0 = acc0 + wo2 * (v0 * rc0);
            acc1 = acc1 + wo2 * (v1 * rc1);
        }
        float4 ov;
        ov.x = w1[q * 4 + 1] + acc0.x + b2v;
        ov.y = w1[q * 4 + 2] + acc0.y + b2v;
        ov.z = w1[q * 4 + 3] + acc1.x + b2v;
        ov.w = w1[q * 4 + 4] + acc1.y + b2v;
        xo4[q] = ov;
    }
}

// ---------------------------------------------------------------------------
__device__ __forceinline__ float stencil_apply(const float* __restrict__ x,
                                               const float* __restrict__ a,
                                               int i, int j) {
    float acc = 0.0f;
#pragma unroll
    for (int di = -1; di <= 1; ++di) {
#pragma unroll
        for (int dj = -1; dj <= 1; ++dj) {
            int ii = i + di, jj = j + dj;
            float v = (ii >= 0 && ii < NN && jj >= 0 && jj < NN)
                          ? x[ii * NN + jj] : 0.0f;
            acc = fmaf(a[(di + 1) * 3 + (dj + 1)], v, acc);
        }
    }
    return acc;
}

__global__ __launch_bounds__(256) void resnorm_kernel(const float* __restrict__ xin,
                                                      const float* __restrict__ f,
                                                      const float* __restrict__ kernelA,
                                                      float* __restrict__ acc) {
    const long long total = (long long)BB * NN * NN;
    float rr = 0.f, f2 = 0.f;
    for (long long p = (long long)blockIdx.x * 256 + threadIdx.x; p < total;
         p += (long long)gridDim.x * 256) {
        int b = (int)(p >> 18);               // NN*NN = 2^18
        int rem = (int)(p & ((1 << 18) - 1));
        int i = rem >> 9, j = rem & 511;
        const float* a = kernelA + b * 9;
        const float* x = xin + (size_t)b * NN * NN;
        float ax = stencil_apply(x, a, i, j);
        float ff = f[p];
        float r = ff - ax;
        rr = fmaf(r, r, rr);
        f2 = fmaf(ff, ff, f2);
    }
#pragma unroll
    for (int off = 32; off > 0; off >>= 1) {
        rr += __shfl_down(rr, off, 64);
        f2 += __shfl_down(f2, off, 64);
    }
    __shared__ float sr[4], sf[4];
    int wave = threadIdx.x >> 6;
    if ((threadIdx.x & 63) == 0) { sr[wave] = rr; sf[wave] = f2; }
    __syncthreads();
    if (threadIdx.x == 0) {
        atomicAdd(&acc[0], sr[0] + sr[1] + sr[2] + sr[3]);
        atomicAdd(&acc[1], sf[0] + sf[1] + sf[2] + sf[3]);
    }
}

__global__ void finalize_kernel(const float* __restrict__ acc, float* __restrict__ out) {
    out[0] = sqrtf(acc[0] / acc[1]);
}

// ---------------------------------------------------------------------------
extern "C" void kernel_launch(void* const* d_in, const int* in_sizes, int n_in,
                              void* d_out, int out_size, void* d_ws, size_t ws_size,
                              hipStream_t stream) {
    const float* f  = (const float*)d_in[0];
    const float* kA = (const float*)d_in[1];
    float*       u  = (float*)d_in[2];   // pristine zeros each launch; used as scratch
    const float* W1 = (const float*)d_in[3];
    const float* b1 = (const float*)d_in[4];
    const float* W2 = (const float*)d_in[5];
    const float* b2 = (const float*)d_in[6];
    float* out = (float*)d_out;

    char* ws = (char*)d_ws;
    float* acc = (float*)ws;                                     // 8 B
    float* xB  = (float*)(ws + 256);                             // 16 MiB
    float* lfa = (float*)(ws + 256 + (size_t)BB * NN * NN * 4);  // 16 MiB

    hipMemsetAsync(acc, 0, 2 * sizeof(float), stream);

    lfa_kernel<<<dim3(NN / 256, NN, BB), 256, 0, stream>>>(kA, lfa);

    dim3 jblk(32, 8);
    dim3 jgrd(NN / OT, NN / OT, BB);

    // cycle 1 (x = 0), cycle 2, cycle 3
    fused_cycle<true><<<jgrd, jblk, 0, stream>>>(u, xB, f, kA, lfa, W1, b1, W2, b2);
    fused_cycle<false><<<jgrd, jblk, 0, stream>>>(xB, u, f, kA, lfa, W1, b1, W2, b2);
    fused_cycle<false><<<jgrd, jblk, 0, stream>>>(u, xB, f, kA, lfa, W1, b1, W2, b2);

    resnorm_kernel<<<2048, 256, 0, stream>>>(xB, f, kA, acc);
    finalize_kernel<<<1, 1, 0, stream>>>(acc, out);
}

// Round 6
// 489.638 us; speedup vs baseline: 1.5321x; 1.5321x over previous
//
#include <hip/hip_runtime.h>
#include <math.h>

#define BB 16
#define NN 512
#define HID 32
#define KCYC 3   // (201-1)/100 + 1

#define HALO 16
#define TW 96        // logical tile width (64 + 2*HALO)
#define TWP 97       // LDS pitch: 97 % 32 == 1 -> conflict-free Phase D (2 lanes/bank)
#define OT 64

// fast tanh-approx GELU: gelu(v) = v / (1 + exp2(K1*v + K2*v^3))
#define GELU_K1 (-2.302208201f)
#define GELU_K2 (-0.102944244f)

// ---------------------------------------------------------------------------
// LFA map: lfa[b,i,j] = |1 - tau * S(theta1, theta2)|^5
// ---------------------------------------------------------------------------
__global__ __launch_bounds__(256) void lfa_kernel(const float* __restrict__ kernelA,
                                                  float* __restrict__ lfa) {
    int j = blockIdx.x * 256 + threadIdx.x;   // col
    int i = blockIdx.y;                       // row
    int b = blockIdx.z;
    const float* a = kernelA + b * 9;
    float a0 = a[0], a1 = a[1], a2 = a[2], a3 = a[3], a4 = a[4];
    float a5 = a[5], a6 = a[6], a7 = a[7], a8 = a[8];

    const float h = 1.0f / (float)(NN + 1);
    const float twopi_h = 6.283185307179586f * h;
    float th1 = twopi_h * (float)(j - NN / 2);
    float th2 = twopi_h * (float)(i - NN / 2);
    float s1, c1, s2, c2;
    sincosf(th1, &s1, &c1);
    sincosf(th2, &s2, &c2);

    float cpp = c1 * c2 - s1 * s2;
    float spp = s1 * c2 + c1 * s2;
    float cpm = c1 * c2 + s1 * s2;
    float spm = s1 * c2 - c1 * s2;

    float re = a4 + (a3 + a5) * c1 + (a1 + a7) * c2
             + (a0 + a8) * cpp + (a2 + a6) * cpm;
    float im = (a5 - a3) * s1 + (a7 - a1) * s2
             + (a8 - a0) * spp + (a2 - a6) * spm;

    float tau = 0.5f / a4;
    float zre = 1.0f - tau * re;
    float zim = -tau * im;
    float m2 = zre * zre + zim * zim;
    float v = m2 * m2 * sqrtf(m2);    // |z|^5

    lfa[(size_t)b * NN * NN + (size_t)i * NN + j] = v;
}

// ---------------------------------------------------------------------------
// One full cycle: 10 Jacobi sweeps (register-resident 12x3 blocks, LDS halo
// exchange only) + fused pointwise-MLP correction (thread-remapped, 1x work)
// Tile 96x96 (pitch 97), output 64x64. After sweep s rings >= s valid;
// correction windows lie in rings >= 15, valid since 10 < 15.
// NO occupancy cap: natural allocation (~116 VGPR, 4 waves/SIMD) is optimal;
// round-4 (+16 VGPR) and round-5 (forced 64 VGPR -> spills) both regressed.
// ---------------------------------------------------------------------------
template <bool FIRST>
__global__ __launch_bounds__(256) void fused_cycle(
        const float* __restrict__ xin, float* __restrict__ xout,
        const float* __restrict__ f, const float* __restrict__ kernelA,
        const float* __restrict__ lfa,
        const float* __restrict__ W1, const float* __restrict__ b1,
        const float* __restrict__ W2, const float* __restrict__ b2) {
    __shared__ float sx[TW * TWP];
    __shared__ float swt[132];    // W1(64) | b1(32) | W2(32) | b2(1)
    const int tx = threadIdx.x;   // 0..31
    const int ty = threadIdx.y;   // 0..7
    const int t  = ty * 32 + tx;
    const int b  = blockIdx.z;
    const int gy0 = blockIdx.y * OT;
    const int gx0 = blockIdx.x * OT;
    const int goi = gy0 - HALO;
    const int goj = gx0 - HALO;
    const float* fg = f + (size_t)b * NN * NN;
    const float* ag = kernelA + b * 9;   // uniform -> s_load
    const float ar0 = ag[0], ar1 = ag[1], ar2 = ag[2], ar3 = ag[3], ar4 = ag[4];
    const float ar5 = ag[5], ar6 = ag[6], ar7 = ag[7], ar8 = ag[8];
    const float tau = 0.5f / ar4;
    // tau-scaled stencil for the sweeps
    const float s0 = tau * ar0, q1 = tau * ar1, q2 = tau * ar2, q3 = tau * ar3;
    const float q4 = tau * ar4, q5 = tau * ar5, q6 = tau * ar6, q7 = tau * ar7;
    const float q8 = tau * ar8;

    // ---- weights -> LDS broadcast array (one-time) ----
    if (t < 129) {
        float w;
        if (t < 64)       w = W1[t];
        else if (t < 96)  w = b1[t - 64];
        else if (t < 128) w = W2[t - 96];
        else              w = b2[0];
        swt[t] = w;
    }

    // ---- Phase A: tile -> LDS ----
    if (FIRST) {
#pragma unroll
        for (int k = 0; k < (TW * TW) / 256; ++k) {
            int idx = t + k * 256;
            int row = idx / TW, col = idx - row * TW;
            sx[row * TWP + col] = 0.f;
        }
    } else {
        const float* xg = xin + (size_t)b * NN * NN;
#pragma unroll
        for (int k = 0; k < (TW * TW) / 256; ++k) {
            int idx = t + k * 256;
            int row = idx / TW, col = idx - row * TW;
            int gi = goi + row, gj = goj + col;
            float v = 0.f;
            if (gi >= 0 && gi < NN && gj >= 0 && gj < NN) v = xg[gi * NN + gj];
            sx[row * TWP + col] = v;
        }
    }

    const int R0 = ty * 12, C0 = tx * 3;

    // masks: cell updates only if tile-interior AND inside global domain
    float vR[12], vC[3];
#pragma unroll
    for (int r = 0; r < 12; ++r) {
        int R = R0 + r, gi = goi + R;
        vR[r] = (R >= 1 && R < TW - 1 && gi >= 0 && gi < NN) ? 1.f : 0.f;
    }
#pragma unroll
    for (int c = 0; c < 3; ++c) {
        int C = C0 + c, gj = goj + C;
        vC[c] = (C >= 1 && C < TW - 1 && gj >= 0 && gj < NN) ? 1.f : 0.f;
    }

    // tau-scaled f for owned cells (0 outside domain)
    float frt[12][3];
#pragma unroll
    for (int r = 0; r < 12; ++r) {
        int gi = goi + R0 + r;
#pragma unroll
        for (int c = 0; c < 3; ++c) {
            int gj = goj + C0 + c;
            frt[r][c] = (gi >= 0 && gi < NN && gj >= 0 && gj < NN)
                            ? tau * fg[gi * NN + gj] : 0.f;
        }
    }

    __syncthreads();   // tile + weights visible

    // ---- Phase B: own cells -> registers ----
    float cur[12][3];
    if (FIRST) {
#pragma unroll
        for (int r = 0; r < 12; ++r) { cur[r][0] = cur[r][1] = cur[r][2] = 0.f; }
    } else {
#pragma unroll
        for (int r = 0; r < 12; ++r) {
            int base = (R0 + r) * TWP + C0;
            cur[r][0] = sx[base]; cur[r][1] = sx[base + 1]; cur[r][2] = sx[base + 2];
        }
    }

    // clamped halo indices (garbage only feeds masked / already-invalid cells)
    const int rT = (R0 == 0) ? 0 : R0 - 1;
    const int rB = (R0 + 12 > TW - 1) ? TW - 1 : R0 + 12;
    const int cL = (C0 == 0) ? 0 : C0 - 1;
    const int cR = (C0 + 3 > TW - 1) ? TW - 1 : C0 + 3;

    // ---- Phase C: 10 sweeps ----
    for (int s = 0; s < 10; ++s) {
        // halo reads (34)
        float top0 = sx[rT * TWP + cL], top1 = sx[rT * TWP + C0],
              top2 = sx[rT * TWP + C0 + 1], top3 = sx[rT * TWP + C0 + 2],
              top4 = sx[rT * TWP + cR];
        float bot0 = sx[rB * TWP + cL], bot1 = sx[rB * TWP + C0],
              bot2 = sx[rB * TWP + C0 + 1], bot3 = sx[rB * TWP + C0 + 2],
              bot4 = sx[rB * TWP + cR];
        float pm0 = top1, pm1v = top2, pm2 = top3;
        float Lm1 = top0, Rm1 = top4;
        float Lc = sx[R0 * TWP + cL], Rc = sx[R0 * TWP + cR];
#pragma unroll
        for (int r = 0; r < 12; ++r) {
            float n0, n1, n2, Lp, Rp;
            if (r < 11) {
                n0 = cur[r + 1][0]; n1 = cur[r + 1][1]; n2 = cur[r + 1][2];
                Lp = sx[(R0 + r + 1) * TWP + cL];
                Rp = sx[(R0 + r + 1) * TWP + cR];
            } else {
                n0 = bot1; n1 = bot2; n2 = bot3; Lp = bot0; Rp = bot4;
            }
            float o0 = cur[r][0], o1 = cur[r][1], o2 = cur[r][2];
            // c = 0
            {
                float ax = s0 * Lm1;
                ax = fmaf(q1, pm0, ax); ax = fmaf(q2, pm1v, ax);
                ax = fmaf(q3, Lc, ax);  ax = fmaf(q4, o0, ax);
                ax = fmaf(q5, o1, ax);  ax = fmaf(q6, Lp, ax);
                ax = fmaf(q7, n0, ax);  ax = fmaf(q8, n1, ax);
                cur[r][0] = fmaf(vR[r] * vC[0], frt[r][0] - ax, o0);
            }
            // c = 1
            {
                float ax = s0 * pm0;
                ax = fmaf(q1, pm1v, ax); ax = fmaf(q2, pm2, ax);
                ax = fmaf(q3, o0, ax);   ax = fmaf(q4, o1, ax);
                ax = fmaf(q5, o2, ax);   ax = fmaf(q6, n0, ax);
                ax = fmaf(q7, n1, ax);   ax = fmaf(q8, n2, ax);
                cur[r][1] = fmaf(vR[r] * vC[1], frt[r][1] - ax, o1);
            }
            // c = 2
            {
                float ax = s0 * pm1v;
                ax = fmaf(q1, pm2, ax); ax = fmaf(q2, Rm1, ax);
                ax = fmaf(q3, o1, ax);  ax = fmaf(q4, o2, ax);
                ax = fmaf(q5, Rc, ax);  ax = fmaf(q6, n1, ax);
                ax = fmaf(q7, n2, ax);  ax = fmaf(q8, Rp, ax);
                cur[r][2] = fmaf(vR[r] * vC[2], frt[r][2] - ax, o2);
            }
            pm0 = o0; pm1v = o1; pm2 = o2;
            Lm1 = Lc; Rm1 = Rc; Lc = Lp; Rc = Rp;
        }
        __syncthreads();   // all halo reads done
        if (s < 9) {
            // write border cells (26)
            int bTop = R0 * TWP + C0, bBot = (R0 + 11) * TWP + C0;
            sx[bTop] = cur[0][0]; sx[bTop + 1] = cur[0][1]; sx[bTop + 2] = cur[0][2];
            sx[bBot] = cur[11][0]; sx[bBot + 1] = cur[11][1]; sx[bBot + 2] = cur[11][2];
#pragma unroll
            for (int r = 1; r < 11; ++r) {
                int base = (R0 + r) * TWP + C0;
                sx[base] = cur[r][0]; sx[base + 2] = cur[r][2];
            }
        } else {
            // final sweep: publish ALL cells for the correction phase
#pragma unroll
            for (int r = 0; r < 12; ++r) {
                int base = (R0 + r) * TWP + C0;
                sx[base] = cur[r][0]; sx[base + 1] = cur[r][1]; sx[base + 2] = cur[r][2];
            }
        }
        __syncthreads();   // writes visible
    }

    // ---- Phase D: remapped correction, exactly 1x MLP work ----
    // thread t -> output row orow = t/4 (0..63), column segment oseg = t%4 (16 cols)
    // With pitch 97: bank = (orow + 16*oseg + k) % 32 -> 2 lanes/bank (free).
    const int orow = t >> 2;
    const int oseg = t & 3;
    const int Rl = HALO + orow;           // 16..79
    const int Cl0 = HALO + oseg * 16;     // 16,32,48,64
    float w0[18], w1[18], w2[18];
#pragma unroll
    for (int k = 0; k < 18; ++k) {
        w0[k] = sx[(Rl - 1) * TWP + Cl0 - 1 + k];
        w1[k] = sx[Rl * TWP + Cl0 - 1 + k];
        w2[k] = sx[(Rl + 1) * TWP + Cl0 - 1 + k];
    }
    const int gi = gy0 + orow;
    const int gjb = gx0 + oseg * 16;
    const float4* f4 = (const float4*)(fg + (size_t)gi * NN + gjb);
    const float4* l4 = (const float4*)(lfa + (size_t)b * NN * NN + (size_t)gi * NN + gjb);
    float fv[16], lv[16];
#pragma unroll
    for (int q = 0; q < 4; ++q) {
        float4 fq = f4[q], lq = l4[q];
        fv[q * 4] = fq.x; fv[q * 4 + 1] = fq.y; fv[q * 4 + 2] = fq.z; fv[q * 4 + 3] = fq.w;
        lv[q * 4] = lq.x; lv[q * 4 + 1] = lq.y; lv[q * 4 + 2] = lq.z; lv[q * 4 + 3] = lq.w;
    }
    float rv[16];
#pragma unroll
    for (int k = 0; k < 16; ++k) {
        float ax = ar0 * w0[k];
        ax = fmaf(ar1, w0[k + 1], ax); ax = fmaf(ar2, w0[k + 2], ax);
        ax = fmaf(ar3, w1[k], ax);     ax = fmaf(ar4, w1[k + 1], ax);
        ax = fmaf(ar5, w1[k + 2], ax); ax = fmaf(ar6, w2[k], ax);
        ax = fmaf(ar7, w2[k + 1], ax); ax = fmaf(ar8, w2[k + 2], ax);
        rv[k] = fv[k] - ax;
    }
    float acc[16];
#pragma unroll
    for (int k = 0; k < 16; ++k) acc[k] = 0.f;
    for (int hh = 0; hh < HID; ++hh) {
        float w1a = swt[2 * hh], w1b = swt[2 * hh + 1];
        float bb = swt[64 + hh], wo = swt[96 + hh];
#pragma unroll
        for (int k = 0; k < 16; ++k) {
            float v = fmaf(w1a, lv[k], fmaf(w1b, rv[k], bb));
            float m = v * fmaf(GELU_K2, v * v, GELU_K1);
            float e = __builtin_amdgcn_exp2f(m);
            float g = v * __builtin_amdgcn_rcpf(1.0f + e);
            acc[k] = fmaf(wo, g, acc[k]);
        }
    }
    const float b2v = swt[128];
    float4* xo4 = (float4*)(xout + (size_t)b * NN * NN + (size_t)gi * NN + gjb);
#pragma unroll
    for (int q = 0; q < 4; ++q) {
        float4 ov;
        ov.x = w1[q * 4 + 1] + acc[q * 4] + b2v;
        ov.y = w1[q * 4 + 2] + acc[q * 4 + 1] + b2v;
        ov.z = w1[q * 4 + 3] + acc[q * 4 + 2] + b2v;
        ov.w = w1[q * 4 + 4] + acc[q * 4 + 3] + b2v;
        xo4[q] = ov;
    }
}

// ---------------------------------------------------------------------------
__device__ __forceinline__ float stencil_apply(const float* __restrict__ x,
                                               const float* __restrict__ a,
                                               int i, int j) {
    float acc = 0.0f;
#pragma unroll
    for (int di = -1; di <= 1; ++di) {
#pragma unroll
        for (int dj = -1; dj <= 1; ++dj) {
            int ii = i + di, jj = j + dj;
            float v = (ii >= 0 && ii < NN && jj >= 0 && jj < NN)
                          ? x[ii * NN + jj] : 0.0f;
            acc = fmaf(a[(di + 1) * 3 + (dj + 1)], v, acc);
        }
    }
    return acc;
}

__global__ __launch_bounds__(256) void resnorm_kernel(const float* __restrict__ xin,
                                                      const float* __restrict__ f,
                                                      const float* __restrict__ kernelA,
                                                      float* __restrict__ acc) {
    const long long total = (long long)BB * NN * NN;
    float rr = 0.f, f2 = 0.f;
    for (long long p = (long long)blockIdx.x * 256 + threadIdx.x; p < total;
         p += (long long)gridDim.x * 256) {
        int b = (int)(p >> 18);               // NN*NN = 2^18
        int rem = (int)(p & ((1 << 18) - 1));
        int i = rem >> 9, j = rem & 511;
        const float* a = kernelA + b * 9;
        const float* x = xin + (size_t)b * NN * NN;
        float ax = stencil_apply(x, a, i, j);
        float ff = f[p];
        float r = ff - ax;
        rr = fmaf(r, r, rr);
        f2 = fmaf(ff, ff, f2);
    }
#pragma unroll
    for (int off = 32; off > 0; off >>= 1) {
        rr += __shfl_down(rr, off, 64);
        f2 += __shfl_down(f2, off, 64);
    }
    __shared__ float sr[4], sf[4];
    int wave = threadIdx.x >> 6;
    if ((threadIdx.x & 63) == 0) { sr[wave] = rr; sf[wave] = f2; }
    __syncthreads();
    if (threadIdx.x == 0) {
        atomicAdd(&acc[0], sr[0] + sr[1] + sr[2] + sr[3]);
        atomicAdd(&acc[1], sf[0] + sf[1] + sf[2] + sf[3]);
    }
}

__global__ void finalize_kernel(const float* __restrict__ acc, float* __restrict__ out) {
    out[0] = sqrtf(acc[0] / acc[1]);
}

// ---------------------------------------------------------------------------
extern "C" void kernel_launch(void* const* d_in, const int* in_sizes, int n_in,
                              void* d_out, int out_size, void* d_ws, size_t ws_size,
                              hipStream_t stream) {
    const float* f  = (const float*)d_in[0];
    const float* kA = (const float*)d_in[1];
    float*       u  = (float*)d_in[2];   // pristine zeros each launch; used as scratch
    const float* W1 = (const float*)d_in[3];
    const float* b1 = (const float*)d_in[4];
    const float* W2 = (const float*)d_in[5];
    const float* b2 = (const float*)d_in[6];
    float* out = (float*)d_out;

    char* ws = (char*)d_ws;
    float* acc = (float*)ws;                                     // 8 B
    float* xB  = (float*)(ws + 256);                             // 16 MiB
    float* lfa = (float*)(ws + 256 + (size_t)BB * NN * NN * 4);  // 16 MiB

    hipMemsetAsync(acc, 0, 2 * sizeof(float), stream);

    lfa_kernel<<<dim3(NN / 256, NN, BB), 256, 0, stream>>>(kA, lfa);

    dim3 jblk(32, 8);
    dim3 jgrd(NN / OT, NN / OT, BB);

    // cycle 1 (x = 0), cycle 2, cycle 3
    fused_cycle<true><<<jgrd, jblk, 0, stream>>>(u, xB, f, kA, lfa, W1, b1, W2, b2);
    fused_cycle<false><<<jgrd, jblk, 0, stream>>>(xB, u, f, kA, lfa, W1, b1, W2, b2);
    fused_cycle<false><<<jgrd, jblk, 0, stream>>>(u, xB, f, kA, lfa, W1, b1, W2, b2);

    resnorm_kernel<<<2048, 256, 0, stream>>>(xB, f, kA, acc);
    finalize_kernel<<<1, 1, 0, stream>>>(acc, out);
}

// Round 7
// 446.714 us; speedup vs baseline: 1.6793x; 1.0961x over previous
//
#include <hip/hip_runtime.h>
#include <math.h>

#define BB 16
#define NN 512
#define HID 32
#define KCYC 3   // (201-1)/100 + 1

#define HALO 16
#define TW 96        // logical tile width (64 + 2*HALO)
#define TWP 97       // LDS pitch: 97 % 32 == 1 -> conflict-free Phase D
#define OT 64

// fast tanh-approx GELU: gelu(v) = v / (1 + exp2(K1*v + K2*v^3))
#define GELU_K1 (-2.302208201f)
#define GELU_K2 (-0.102944244f)

// ---------------------------------------------------------------------------
// LFA map: lfa[b,i,j] = |1 - tau * S(theta1, theta2)|^5
// ---------------------------------------------------------------------------
__global__ __launch_bounds__(256) void lfa_kernel(const float* __restrict__ kernelA,
                                                  float* __restrict__ lfa) {
    int j = blockIdx.x * 256 + threadIdx.x;   // col
    int i = blockIdx.y;                       // row
    int b = blockIdx.z;
    const float* a = kernelA + b * 9;
    float a0 = a[0], a1 = a[1], a2 = a[2], a3 = a[3], a4 = a[4];
    float a5 = a[5], a6 = a[6], a7 = a[7], a8 = a[8];

    const float h = 1.0f / (float)(NN + 1);
    const float twopi_h = 6.283185307179586f * h;
    float th1 = twopi_h * (float)(j - NN / 2);
    float th2 = twopi_h * (float)(i - NN / 2);
    float s1, c1, s2, c2;
    sincosf(th1, &s1, &c1);
    sincosf(th2, &s2, &c2);

    float cpp = c1 * c2 - s1 * s2;
    float spp = s1 * c2 + c1 * s2;
    float cpm = c1 * c2 + s1 * s2;
    float spm = s1 * c2 - c1 * s2;

    float re = a4 + (a3 + a5) * c1 + (a1 + a7) * c2
             + (a0 + a8) * cpp + (a2 + a6) * cpm;
    float im = (a5 - a3) * s1 + (a7 - a1) * s2
             + (a8 - a0) * spp + (a2 - a6) * spm;

    float tau = 0.5f / a4;
    float zre = 1.0f - tau * re;
    float zim = -tau * im;
    float m2 = zre * zre + zim * zim;
    float v = m2 * m2 * sqrtf(m2);    // |z|^5

    lfa[(size_t)b * NN * NN + (size_t)i * NN + j] = v;
}

// ---------------------------------------------------------------------------
// One full cycle: 10 Jacobi sweeps (register-resident 12x3 blocks, LDS halo
// exchange only) + fused pointwise-MLP correction (thread-remapped, 1x work)
// Guard-ring LDS tile: logical (row,col) in [-1,96]^2, physically in-bounds;
// guards zeroed once -> NO clamps, and every LDS access is one base pointer
// + compile-time immediate (keeps address-register count minimal; round-4/6
// showed naive pitch-97 indexing costs +16 VGPR -> occupancy cliff).
// ---------------------------------------------------------------------------
template <bool FIRST>
__global__ __launch_bounds__(256) void fused_cycle(
        const float* __restrict__ xin, float* __restrict__ xout,
        const float* __restrict__ f, const float* __restrict__ kernelA,
        const float* __restrict__ lfa,
        const float* __restrict__ W1, const float* __restrict__ b1,
        const float* __restrict__ W2, const float* __restrict__ b2) {
    __shared__ float sxraw[98 * TWP + 2];
    float* sx = sxraw + TWP + 1;   // logical origin (0,0); row r col c -> sx[r*TWP+c]
    const int tx = threadIdx.x;   // 0..31
    const int ty = threadIdx.y;   // 0..7
    const int t  = ty * 32 + tx;
    const int b  = blockIdx.z;
    const int gy0 = blockIdx.y * OT;
    const int gx0 = blockIdx.x * OT;
    const int goi = gy0 - HALO;
    const int goj = gx0 - HALO;
    const float* fg = f + (size_t)b * NN * NN;
    const float* ag = kernelA + b * 9;   // uniform -> s_load
    const float ar0 = ag[0], ar1 = ag[1], ar2 = ag[2], ar3 = ag[3], ar4 = ag[4];
    const float ar5 = ag[5], ar6 = ag[6], ar7 = ag[7], ar8 = ag[8];
    const float tau = 0.5f / ar4;
    // tau-scaled stencil for the sweeps
    const float s0 = tau * ar0, q1 = tau * ar1, q2 = tau * ar2, q3 = tau * ar3;
    const float q4 = tau * ar4, q5 = tau * ar5, q6 = tau * ar6, q7 = tau * ar7;
    const float q8 = tau * ar8;

    // ---- zero the guard ring (top band, shared L/R col guards, bottom band)
    if (t < 98) sxraw[t] = 0.f;                 // logical row -1, col -1..96
    if (t < 96) sxraw[97 + 97 * t] = 0.f;       // col -1 of row t (== col 96 of row t-1)
    if (t < 98) sxraw[9409 + t] = 0.f;          // logical row 96, col -1..96

    // ---- Phase A: tile -> LDS (interior 96x96) ----
    if (FIRST) {
#pragma unroll
        for (int k = 0; k < (TW * TW) / 256; ++k) {
            int idx = t + k * 256;
            int row = idx / TW, col = idx - row * TW;
            sx[row * TWP + col] = 0.f;
        }
    } else {
        const float* xg = xin + (size_t)b * NN * NN;
#pragma unroll
        for (int k = 0; k < (TW * TW) / 256; ++k) {
            int idx = t + k * 256;
            int row = idx / TW, col = idx - row * TW;
            int gi = goi + row, gj = goj + col;
            float v = 0.f;
            if (gi >= 0 && gi < NN && gj >= 0 && gj < NN) v = xg[gi * NN + gj];
            sx[row * TWP + col] = v;
        }
    }

    const int R0 = ty * 12, C0 = tx * 3;

    // single base pointers: all LDS traffic below is base + compile-time imm
    const float* pb  = sx + (R0 - 1) * TWP + (C0 - 1);  // extended-block origin
    float*       pwv = sx + R0 * TWP + C0;              // owned-cell origin

    // masks: cell updates only if tile-interior AND inside global domain
    float vR[12], vC[3];
#pragma unroll
    for (int r = 0; r < 12; ++r) {
        int R = R0 + r, gi = goi + R;
        vR[r] = (R >= 1 && R < TW - 1 && gi >= 0 && gi < NN) ? 1.f : 0.f;
    }
#pragma unroll
    for (int c = 0; c < 3; ++c) {
        int C = C0 + c, gj = goj + C;
        vC[c] = (C >= 1 && C < TW - 1 && gj >= 0 && gj < NN) ? 1.f : 0.f;
    }

    // tau-scaled f for owned cells (0 outside domain)
    float frt[12][3];
#pragma unroll
    for (int r = 0; r < 12; ++r) {
        int gi = goi + R0 + r;
#pragma unroll
        for (int c = 0; c < 3; ++c) {
            int gj = goj + C0 + c;
            frt[r][c] = (gi >= 0 && gi < NN && gj >= 0 && gj < NN)
                            ? tau * fg[gi * NN + gj] : 0.f;
        }
    }

    __syncthreads();   // tile + guards visible

    // ---- Phase B: own cells -> registers ----
    float cur[12][3];
    if (FIRST) {
#pragma unroll
        for (int r = 0; r < 12; ++r) { cur[r][0] = cur[r][1] = cur[r][2] = 0.f; }
    } else {
#pragma unroll
        for (int r = 0; r < 12; ++r) {
            cur[r][0] = pwv[r * TWP];
            cur[r][1] = pwv[r * TWP + 1];
            cur[r][2] = pwv[r * TWP + 2];
        }
    }

    // ---- Phase C: 10 sweeps ----
    for (int s = 0; s < 10; ++s) {
        // halo reads (34), all immediate offsets off pb
        float top0 = pb[0], top1 = pb[1], top2 = pb[2], top3 = pb[3], top4 = pb[4];
        float bot0 = pb[13 * TWP],     bot1 = pb[13 * TWP + 1],
              bot2 = pb[13 * TWP + 2], bot3 = pb[13 * TWP + 3],
              bot4 = pb[13 * TWP + 4];
        float pm0 = top1, pm1v = top2, pm2 = top3;
        float Lm1 = top0, Rm1 = top4;
        float Lc = pb[TWP], Rc = pb[TWP + 4];
#pragma unroll
        for (int r = 0; r < 12; ++r) {
            float n0, n1, n2, Lp, Rp;
            if (r < 11) {
                n0 = cur[r + 1][0]; n1 = cur[r + 1][1]; n2 = cur[r + 1][2];
                Lp = pb[(r + 2) * TWP];
                Rp = pb[(r + 2) * TWP + 4];
            } else {
                n0 = bot1; n1 = bot2; n2 = bot3; Lp = bot0; Rp = bot4;
            }
            float o0 = cur[r][0], o1 = cur[r][1], o2 = cur[r][2];
            // c = 0
            {
                float ax = s0 * Lm1;
                ax = fmaf(q1, pm0, ax); ax = fmaf(q2, pm1v, ax);
                ax = fmaf(q3, Lc, ax);  ax = fmaf(q4, o0, ax);
                ax = fmaf(q5, o1, ax);  ax = fmaf(q6, Lp, ax);
                ax = fmaf(q7, n0, ax);  ax = fmaf(q8, n1, ax);
                cur[r][0] = fmaf(vR[r] * vC[0], frt[r][0] - ax, o0);
            }
            // c = 1
            {
                float ax = s0 * pm0;
                ax = fmaf(q1, pm1v, ax); ax = fmaf(q2, pm2, ax);
                ax = fmaf(q3, o0, ax);   ax = fmaf(q4, o1, ax);
                ax = fmaf(q5, o2, ax);   ax = fmaf(q6, n0, ax);
                ax = fmaf(q7, n1, ax);   ax = fmaf(q8, n2, ax);
                cur[r][1] = fmaf(vR[r] * vC[1], frt[r][1] - ax, o1);
            }
            // c = 2
            {
                float ax = s0 * pm1v;
                ax = fmaf(q1, pm2, ax); ax = fmaf(q2, Rm1, ax);
                ax = fmaf(q3, o1, ax);  ax = fmaf(q4, o2, ax);
                ax = fmaf(q5, Rc, ax);  ax = fmaf(q6, n1, ax);
                ax = fmaf(q7, n2, ax);  ax = fmaf(q8, Rp, ax);
                cur[r][2] = fmaf(vR[r] * vC[2], frt[r][2] - ax, o2);
            }
            pm0 = o0; pm1v = o1; pm2 = o2;
            Lm1 = Lc; Rm1 = Rc; Lc = Lp; Rc = Rp;
        }
        __syncthreads();   // all halo reads done
        if (s < 9) {
            // write border cells (26)
            pwv[0] = cur[0][0]; pwv[1] = cur[0][1]; pwv[2] = cur[0][2];
            pwv[11 * TWP] = cur[11][0]; pwv[11 * TWP + 1] = cur[11][1];
            pwv[11 * TWP + 2] = cur[11][2];
#pragma unroll
            for (int r = 1; r < 11; ++r) {
                pwv[r * TWP] = cur[r][0];
                pwv[r * TWP + 2] = cur[r][2];
            }
        } else {
            // final sweep: publish ALL cells for the correction phase
#pragma unroll
            for (int r = 0; r < 12; ++r) {
                pwv[r * TWP] = cur[r][0];
                pwv[r * TWP + 1] = cur[r][1];
                pwv[r * TWP + 2] = cur[r][2];
            }
        }
        __syncthreads();   // writes visible
    }

    // ---- Phase D: remapped correction, exactly 1x MLP work ----
    // thread t -> output row orow = t/4 (0..63), column segment oseg = t%4 (16 cols)
    // Pitch 97: bank = orow + 16*oseg + k + const (mod 32) -> 2 lanes/bank (free).
    const int orow = t >> 2;
    const int oseg = t & 3;
    const int Rl = HALO + orow;           // 16..79
    const int Cl0 = HALO + oseg * 16;     // 16,32,48,64
    const float* pw = sx + (Rl - 1) * TWP + (Cl0 - 1);   // single base + imm
    float w0[18], w1[18], w2[18];
#pragma unroll
    for (int k = 0; k < 18; ++k) {
        w0[k] = pw[k];
        w1[k] = pw[TWP + k];
        w2[k] = pw[2 * TWP + k];
    }
    const int gi = gy0 + orow;
    const int gjb = gx0 + oseg * 16;
    const float4* f4 = (const float4*)(fg + (size_t)gi * NN + gjb);
    const float4* l4 = (const float4*)(lfa + (size_t)b * NN * NN + (size_t)gi * NN + gjb);
    float fv[16], lv[16];
#pragma unroll
    for (int q = 0; q < 4; ++q) {
        float4 fq = f4[q], lq = l4[q];
        fv[q * 4] = fq.x; fv[q * 4 + 1] = fq.y; fv[q * 4 + 2] = fq.z; fv[q * 4 + 3] = fq.w;
        lv[q * 4] = lq.x; lv[q * 4 + 1] = lq.y; lv[q * 4 + 2] = lq.z; lv[q * 4 + 3] = lq.w;
    }
    float rv[16];
#pragma unroll
    for (int k = 0; k < 16; ++k) {
        float ax = ar0 * w0[k];
        ax = fmaf(ar1, w0[k + 1], ax); ax = fmaf(ar2, w0[k + 2], ax);
        ax = fmaf(ar3, w1[k], ax);     ax = fmaf(ar4, w1[k + 1], ax);
        ax = fmaf(ar5, w1[k + 2], ax); ax = fmaf(ar6, w2[k], ax);
        ax = fmaf(ar7, w2[k + 1], ax); ax = fmaf(ar8, w2[k + 2], ax);
        rv[k] = fv[k] - ax;
    }
    float acc[16];
#pragma unroll
    for (int k = 0; k < 16; ++k) acc[k] = 0.f;
    for (int hh = 0; hh < HID; ++hh) {
        float w1a = W1[2 * hh], w1b = W1[2 * hh + 1], bb = b1[hh], wo = W2[hh];
#pragma unroll
        for (int k = 0; k < 16; ++k) {
            float v = fmaf(w1a, lv[k], fmaf(w1b, rv[k], bb));
            float m = v * fmaf(GELU_K2, v * v, GELU_K1);
            float e = __builtin_amdgcn_exp2f(m);
            float g = v * __builtin_amdgcn_rcpf(1.0f + e);
            acc[k] = fmaf(wo, g, acc[k]);
        }
    }
    const float b2v = b2[0];
    float4* xo4 = (float4*)(xout + (size_t)b * NN * NN + (size_t)gi * NN + gjb);
#pragma unroll
    for (int q = 0; q < 4; ++q) {
        float4 ov;
        ov.x = w1[q * 4 + 1] + acc[q * 4] + b2v;
        ov.y = w1[q * 4 + 2] + acc[q * 4 + 1] + b2v;
        ov.z = w1[q * 4 + 3] + acc[q * 4 + 2] + b2v;
        ov.w = w1[q * 4 + 4] + acc[q * 4 + 3] + b2v;
        xo4[q] = ov;
    }
}

// ---------------------------------------------------------------------------
__device__ __forceinline__ float stencil_apply(const float* __restrict__ x,
                                               const float* __restrict__ a,
                                               int i, int j) {
    float acc = 0.0f;
#pragma unroll
    for (int di = -1; di <= 1; ++di) {
#pragma unroll
        for (int dj = -1; dj <= 1; ++dj) {
            int ii = i + di, jj = j + dj;
            float v = (ii >= 0 && ii < NN && jj >= 0 && jj < NN)
                          ? x[ii * NN + jj] : 0.0f;
            acc = fmaf(a[(di + 1) * 3 + (dj + 1)], v, acc);
        }
    }
    return acc;
}

__global__ __launch_bounds__(256) void resnorm_kernel(const float* __restrict__ xin,
                                                      const float* __restrict__ f,
                                                      const float* __restrict__ kernelA,
                                                      float* __restrict__ acc) {
    const long long total = (long long)BB * NN * NN;
    float rr = 0.f, f2 = 0.f;
    for (long long p = (long long)blockIdx.x * 256 + threadIdx.x; p < total;
         p += (long long)gridDim.x * 256) {
        int b = (int)(p >> 18);               // NN*NN = 2^18
        int rem = (int)(p & ((1 << 18) - 1));
        int i = rem >> 9, j = rem & 511;
        const float* a = kernelA + b * 9;
        const float* x = xin + (size_t)b * NN * NN;
        float ax = stencil_apply(x, a, i, j);
        float ff = f[p];
        float r = ff - ax;
        rr = fmaf(r, r, rr);
        f2 = fmaf(ff, ff, f2);
    }
#pragma unroll
    for (int off = 32; off > 0; off >>= 1) {
        rr += __shfl_down(rr, off, 64);
        f2 += __shfl_down(f2, off, 64);
    }
    __shared__ float sr[4], sf[4];
    int wave = threadIdx.x >> 6;
    if ((threadIdx.x & 63) == 0) { sr[wave] = rr; sf[wave] = f2; }
    __syncthreads();
    if (threadIdx.x == 0) {
        atomicAdd(&acc[0], sr[0] + sr[1] + sr[2] + sr[3]);
        atomicAdd(&acc[1], sf[0] + sf[1] + sf[2] + sf[3]);
    }
}

__global__ void finalize_kernel(const float* __restrict__ acc, float* __restrict__ out) {
    out[0] = sqrtf(acc[0] / acc[1]);
}

// ---------------------------------------------------------------------------
extern "C" void kernel_launch(void* const* d_in, const int* in_sizes, int n_in,
                              void* d_out, int out_size, void* d_ws, size_t ws_size,
                              hipStream_t stream) {
    const float* f  = (const float*)d_in[0];
    const float* kA = (const float*)d_in[1];
    float*       u  = (float*)d_in[2];   // pristine zeros each launch; used as scratch
    const float* W1 = (const float*)d_in[3];
    const float* b1 = (const float*)d_in[4];
    const float* W2 = (const float*)d_in[5];
    const float* b2 = (const float*)d_in[6];
    float* out = (float*)d_out;

    char* ws = (char*)d_ws;
    float* acc = (float*)ws;                                     // 8 B
    float* xB  = (float*)(ws + 256);                             // 16 MiB
    float* lfa = (float*)(ws + 256 + (size_t)BB * NN * NN * 4);  // 16 MiB

    hipMemsetAsync(acc, 0, 2 * sizeof(float), stream);

    lfa_kernel<<<dim3(NN / 256, NN, BB), 256, 0, stream>>>(kA, lfa);

    dim3 jblk(32, 8);
    dim3 jgrd(NN / OT, NN / OT, BB);

    // cycle 1 (x = 0), cycle 2, cycle 3
    fused_cycle<true><<<jgrd, jblk, 0, stream>>>(u, xB, f, kA, lfa, W1, b1, W2, b2);
    fused_cycle<false><<<jgrd, jblk, 0, stream>>>(xB, u, f, kA, lfa, W1, b1, W2, b2);
    fused_cycle<false><<<jgrd, jblk, 0, stream>>>(u, xB, f, kA, lfa, W1, b1, W2, b2);

    resnorm_kernel<<<2048, 256, 0, stream>>>(xB, f, kA, acc);
    finalize_kernel<<<1, 1, 0, stream>>>(acc, out);
}